// Round 4
// baseline (779.449 us; speedup 1.0000x reference)
//
#include <hip/hip_runtime.h>

typedef float nfloat4 __attribute__((ext_vector_type(4)));

// ---------------- workspace layout (u32 indices) ----------------
#define WS_CANDCNT 0
#define WS_B1      1
#define WS_K2      2
#define WS_PFX     3
#define WS_K3      4
#define WS_BAR     8              // grid-barrier ticket counter (memset to 0 pre-launch)
#define WS_HIST1   16
#define WS_HIST2   272            // 16 + 256
#define WS_HIST3   4368           // 272 + 4096
#define WS_ZEND    8464           // end of memset-zeroed header
#define WS_CAND    8464           // candV[cap] floats, then candI[cap] u32

#define STASH 2048
#define NTHR  1024

// Monotone key: larger float -> larger unsigned.
__device__ __forceinline__ unsigned fkey(float f) {
  unsigned x = __float_as_uint(f);
  return x ^ ((x & 0x80000000u) ? 0xFFFFFFFFu : 0x80000000u);
}
__device__ __forceinline__ float unkey(unsigned u) {
  unsigned x = u ^ ((u & 0x80000000u) ? 0x80000000u : 0xFFFFFFFFu);
  return __uint_as_float(x);
}

// ---- custom grid barrier (replaces cg::grid.sync, measured ~176us/sync in R3) ----
// Ticket barrier: one agent-scope atomicAdd arrival per block; thread-0 spins with
// s_sleep backoff; __threadfence on both sides for cross-XCD visibility (same
// fence discipline that R3 proved correct, absmax=0). Requires co-resident grid
// (hipLaunchCooperativeKernel) and uniform control flow — both hold.
__device__ __forceinline__ void gbar(unsigned* ctr, unsigned target) {
  __threadfence();                       // release: prior writes visible device-wide
  __syncthreads();                       // whole block arrived
  if (threadIdx.x == 0) {
    __hip_atomic_fetch_add(ctr, 1u, __ATOMIC_RELEASE, __HIP_MEMORY_SCOPE_AGENT);
    while (__hip_atomic_load(ctr, __ATOMIC_ACQUIRE, __HIP_MEMORY_SCOPE_AGENT) < target)
      __builtin_amdgcn_s_sleep(8);
  }
  __syncthreads();                       // block waits for thread 0
  __threadfence();                       // acquire-side invalidate for all threads
}

// ================= 1024-thread-block primitives (mega kernel) =================
__device__ __forceinline__ unsigned scan1024(unsigned v, unsigned* sh16) {
  const int t = threadIdx.x;
  unsigned p = v;
#pragma unroll
  for (int off = 1; off < 64; off <<= 1) {
    unsigned y = __shfl_up(p, off);
    if ((t & 63) >= off) p += y;
  }
  if ((t & 63) == 63) sh16[t >> 6] = p;
  __syncthreads();
  unsigned wo = 0;
  for (int w = 0; w < (t >> 6); ++w) wo += sh16[w];
  __syncthreads();
  return p + wo;
}

__device__ __forceinline__ uint2 sel256_w(const unsigned* __restrict__ gh, unsigned k,
                                          unsigned* sh16, unsigned* sel2) {
  const int t = threadIdx.x;
  unsigned cnt = (t < 256) ? gh[255 - t] : 0u;
  unsigned incl = scan1024(cnt, sh16);
  unsigned excl = incl - cnt;
  if (t < 256 && excl < k && incl >= k) { sel2[0] = (unsigned)(255 - t); sel2[1] = k - excl; }
  __syncthreads();
  uint2 r; r.x = sel2[0]; r.y = sel2[1];
  __syncthreads();
  return r;
}

__device__ __forceinline__ uint2 sel4096_w(const unsigned* __restrict__ gh, unsigned k,
                                           unsigned* sh16, unsigned* sel2) {
  const int t = threadIdx.x;
  unsigned loc[4]; unsigned s = 0;
  const int base = 4095 - t * 4;
#pragma unroll
  for (int j = 0; j < 4; ++j) { unsigned c = gh[base - j]; loc[j] = c; s += c; }
  unsigned incl = scan1024(s, sh16);
  unsigned excl = incl - s;
  if (excl < k && incl >= k) {
    unsigned cum = excl; int j = 0;
    while (cum + loc[j] < k) { cum += loc[j]; ++j; }
    sel2[0] = (unsigned)(base - j); sel2[1] = k - cum;
  }
  __syncthreads();
  uint2 r; r.x = sel2[0]; r.y = sel2[1];
  __syncthreads();
  return r;
}

// ============================ fused cooperative kernel ============================
// Phases: A hist1 | B sel1(redundant/block) | C scatter | D candhist2(128 blk) |
// E sel2+candhist3(128 blk) | F sel3+fixup. 4 custom barriers; ws header zeroed
// by hipMemsetAsync before launch (removes R3's phase 0 + one barrier).
__global__ void __launch_bounds__(NTHR, 8) mega_kernel(
    const float* __restrict__ e, const float* __restrict__ m, const float* __restrict__ d,
    const int* __restrict__ maxf, float* __restrict__ out, unsigned* __restrict__ ws,
    unsigned cap, int n0v, int n1v, int n2v,
    int e_blks, int m_blks, int nblocks, long long n) {
  const int t = threadIdx.x;
  const int bid = blockIdx.x;
  const int NB = gridDim.x;
  unsigned* bar = ws + WS_BAR;

  __shared__ unsigned shraw[256 * 32];   // 32 KB, overlaid per phase
  __shared__ unsigned sh16[16];
  __shared__ unsigned sel2[2];
  __shared__ unsigned sh_cnt, sh_base;

  // ---- phase A: 8-bit MSB histogram (verified body) ----
  {
    unsigned* h = shraw;
    for (int i = t; i < 256 * 32; i += NTHR) h[i] = 0u;
    __syncthreads();
    const unsigned sub = t & 31u;
    const int gid = bid * NTHR + t;
    const int G = NB * NTHR;
    auto acc1 = [&](float4 f) {
      atomicAdd(&h[((fkey(f.x) >> 24) << 5) | sub], 1u);
      atomicAdd(&h[((fkey(f.y) >> 24) << 5) | sub], 1u);
      atomicAdd(&h[((fkey(f.z) >> 24) << 5) | sub], 1u);
      atomicAdd(&h[((fkey(f.w) >> 24) << 5) | sub], 1u);
    };
    auto sweep = [&](const float* src, int nv) {
      const float4* a4 = (const float4*)src;
      int v = gid;
      for (; v + 3 * G < nv; v += 4 * G) {
        float4 f0 = a4[v];
        float4 f1 = a4[v + G];
        float4 f2 = a4[v + 2 * G];
        float4 f3 = a4[v + 3 * G];
        acc1(f0); acc1(f1); acc1(f2); acc1(f3);
      }
      for (; v < nv; v += G) acc1(a4[v]);
    };
    sweep(e, n0v);
    sweep(m, n1v);
    sweep(d, n2v);
    __syncthreads();
    if (t < 256) {
      unsigned s = 0;
#pragma unroll
      for (int j = 0; j < 32; ++j) s += h[(t << 5) + ((t + j) & 31)];
      if (s) atomicAdd(&ws[WS_HIST1 + t], s);
    }
  }
  gbar(bar, (unsigned)NB * 1u);

  // ---- phase B: select1, redundant per block ----
  const long long kk = (long long)maxf[0] + 1;
  const bool bigk = (kk > n);          // grid-uniform
  unsigned b1, k2 = 0;
  if (bigk) {
    b1 = 0x80u;                        // thresh = +0.0f path
  } else {
    uint2 r1 = sel256_w(ws + WS_HIST1, (unsigned)kk, sh16, sel2);
    b1 = r1.x; k2 = r1.y;
  }

  // ---- phase C: scatter, grid-stride tiles, one stash flush per block ----
  {
    float*    sh_v = (float*)shraw;        // [STASH]
    unsigned* sh_i = shraw + STASH;        // [STASH]
    if (t == 0) sh_cnt = 0u;
    __syncthreads();
    float* gcV = (float*)(ws + WS_CAND);
    unsigned* gcI = ws + WS_CAND + cap;

    for (int tile = bid; tile < nblocks; tile += NB) {
      const float4* in4;
      if (tile < e_blks)               in4 = (const float4*)e + (long long)tile * 2048;
      else if (tile < e_blks + m_blks) in4 = (const float4*)m + (long long)(tile - e_blks) * 2048;
      else                             in4 = (const float4*)d + (long long)(tile - e_blks - m_blks) * 2048;
      const int out_base_v = tile * 2048;
      nfloat4* out4 = (nfloat4*)out + out_base_v;

      auto emit1 = [&](float4 f, int v) {
        unsigned kx = fkey(f.x), ky = fkey(f.y), kz = fkey(f.z), kw = fkey(f.w);
        nfloat4 o;
        o.x = ((kx >> 24) >= b1) ? f.x : 0.0f;
        o.y = ((ky >> 24) >= b1) ? f.y : 0.0f;
        o.z = ((kz >> 24) >= b1) ? f.z : 0.0f;
        o.w = ((kw >> 24) >= b1) ? f.w : 0.0f;
        __builtin_nontemporal_store(o, &out4[v]);
        unsigned ks[4] = {kx, ky, kz, kw};
        float fs[4] = {f.x, f.y, f.z, f.w};
#pragma unroll
        for (int cc = 0; cc < 4; ++cc) {
          if ((ks[cc] >> 24) == b1) {
            unsigned idx = (unsigned)(out_base_v + v) * 4u + (unsigned)cc;
            unsigned pos = atomicAdd(&sh_cnt, 1u);
            if (pos < STASH) { sh_v[pos] = fs[cc]; sh_i[pos] = idx; }
            else {  // statistically never; correct fallback
              unsigned g = atomicAdd(&ws[WS_CANDCNT], 1u);
              gcV[g] = fs[cc]; gcI[g] = idx;
            }
          }
        }
      };
      float4 f0 = in4[t];
      float4 f1 = in4[1024 + t];
      emit1(f0, t);
      emit1(f1, 1024 + t);
    }

    __syncthreads();
    if (t == 0) {
      unsigned tot = sh_cnt < STASH ? sh_cnt : STASH;
      sh_base = tot ? atomicAdd(&ws[WS_CANDCNT], tot) : 0u;
      sh_cnt = tot;
    }
    __syncthreads();
    const unsigned tot = sh_cnt;
    const unsigned base = sh_base;
    for (unsigned i = t; i < tot; i += NTHR) {
      gcV[base + i] = sh_v[i];
      gcI[base + i] = sh_i[i];
    }
  }
  gbar(bar, (unsigned)NB * 2u);

  const unsigned cnt0 = ws[WS_CANDCNT];
  const unsigned cnt = cnt0 > cap ? cap : cnt0;
  const float* candV = (const float*)(ws + WS_CAND);
  const unsigned* candI = ws + WS_CAND + cap;
  const int chb = NB < 128 ? NB : 128;   // few-block candhist (R1 lesson: keep
                                         // per-block LDS aggregation factor high)

  // ---- phase D: stage-2 12-bit histogram over candidates ----
  if (!bigk && bid < chb) {
    unsigned* sh_hist = shraw;
    for (int i = t; i < 4096; i += NTHR) sh_hist[i] = 0u;
    __syncthreads();
    for (unsigned i = (unsigned)bid * NTHR + t; i < cnt; i += (unsigned)chb * NTHR)
      atomicAdd(&sh_hist[(fkey(candV[i]) >> 12) & 0xFFFu], 1u);
    __syncthreads();
    for (int i = t; i < 4096; i += NTHR) {
      unsigned v = sh_hist[i];
      if (v) atomicAdd(&ws[WS_HIST2 + i], v);
    }
  }
  gbar(bar, (unsigned)NB * 3u);

  // ---- phase E: select2 (redundant per block) + stage-3 histogram ----
  unsigned pfx = 0, k3 = 0;
  if (!bigk) {
    uint2 r2 = sel4096_w(ws + WS_HIST2, k2, sh16, sel2);
    pfx = (b1 << 12) | r2.x; k3 = r2.y;
    if (bid < chb) {
      unsigned* sh_hist = shraw;
      for (int i = t; i < 4096; i += NTHR) sh_hist[i] = 0u;
      __syncthreads();
      for (unsigned i = (unsigned)bid * NTHR + t; i < cnt; i += (unsigned)chb * NTHR) {
        unsigned u = fkey(candV[i]);
        if ((u >> 12) == pfx) atomicAdd(&sh_hist[u & 0xFFFu], 1u);
      }
      __syncthreads();
      for (int i = t; i < 4096; i += NTHR) {
        unsigned v = sh_hist[i];
        if (v) atomicAdd(&ws[WS_HIST3 + i], v);
      }
    }
  }
  gbar(bar, (unsigned)NB * 4u);

  // ---- phase F: select3 (redundant per block) + fixup ----
  if (!bigk) {
    uint2 r3 = sel4096_w(ws + WS_HIST3, k3, sh16, sel2);
    const float th = unkey((pfx << 12) | r3.x);
    for (unsigned i = (unsigned)bid * NTHR + t; i < cnt; i += (unsigned)NB * NTHR) {
      float f = candV[i];
      if (f < th) out[candI[i]] = 0.0f;
    }
  }
}

// ======================= fallback: proven R2 kernel chain =======================
__device__ __forceinline__ unsigned block_scan_incl(unsigned v, unsigned* sh4) {
  const int t = threadIdx.x;
  unsigned p = v;
#pragma unroll
  for (int off = 1; off < 64; off <<= 1) {
    unsigned y = __shfl_up(p, off);
    if ((t & 63) >= off) p += y;
  }
  if ((t & 63) == 63) sh4[t >> 6] = p;
  __syncthreads();
  unsigned wo = 0;
  for (int w = 0; w < (t >> 6); ++w) wo += sh4[w];
  __syncthreads();
  return p + wo;
}

__device__ __forceinline__ uint2 select_desc256(const unsigned* __restrict__ gh,
                                                unsigned k, unsigned* sh4, unsigned* sel2) {
  const int t = threadIdx.x;
  unsigned cnt = gh[255 - t];
  unsigned incl = block_scan_incl(cnt, sh4);
  unsigned excl = incl - cnt;
  if (excl < k && incl >= k) { sel2[0] = (unsigned)(255 - t); sel2[1] = k - excl; }
  __syncthreads();
  uint2 r; r.x = sel2[0]; r.y = sel2[1];
  __syncthreads();
  return r;
}

__device__ __forceinline__ uint2 select_desc4096(const unsigned* __restrict__ gh,
                                                 unsigned k, unsigned* sh4, unsigned* sel2) {
  const int t = threadIdx.x;
  unsigned loc[16]; unsigned s = 0;
  const int base = 4095 - t * 16;
#pragma unroll
  for (int j = 0; j < 16; ++j) { unsigned c = gh[base - j]; loc[j] = c; s += c; }
  unsigned incl = block_scan_incl(s, sh4);
  unsigned excl = incl - s;
  if (excl < k && incl >= k) {
    unsigned cum = excl; int j = 0;
    while (cum + loc[j] < k) { cum += loc[j]; ++j; }
    sel2[0] = (unsigned)(base - j); sel2[1] = k - cum;
  }
  __syncthreads();
  uint2 r; r.x = sel2[0]; r.y = sel2[1];
  __syncthreads();
  return r;
}

__global__ void __launch_bounds__(1024) hist1_kernel(
    const float* __restrict__ e, const float* __restrict__ m,
    const float* __restrict__ d, int n0v, int n1v, int n2v,
    unsigned* __restrict__ ws) {
  __shared__ unsigned h[256 * 32];
  for (int i = threadIdx.x; i < 256 * 32; i += 1024) h[i] = 0u;
  __syncthreads();
  const unsigned sub = threadIdx.x & 31u;
  const int gid = blockIdx.x * 1024 + threadIdx.x;
  const int G = gridDim.x * 1024;
  auto acc1 = [&](float4 f) {
    atomicAdd(&h[((fkey(f.x) >> 24) << 5) | sub], 1u);
    atomicAdd(&h[((fkey(f.y) >> 24) << 5) | sub], 1u);
    atomicAdd(&h[((fkey(f.z) >> 24) << 5) | sub], 1u);
    atomicAdd(&h[((fkey(f.w) >> 24) << 5) | sub], 1u);
  };
  auto sweep = [&](const float* src, int nv) {
    const float4* a4 = (const float4*)src;
    int v = gid;
    for (; v + 3 * G < nv; v += 4 * G) {
      float4 f0 = a4[v]; float4 f1 = a4[v + G];
      float4 f2 = a4[v + 2 * G]; float4 f3 = a4[v + 3 * G];
      acc1(f0); acc1(f1); acc1(f2); acc1(f3);
    }
    for (; v < nv; v += G) acc1(a4[v]);
  };
  sweep(e, n0v); sweep(m, n1v); sweep(d, n2v);
  __syncthreads();
  const int t = threadIdx.x;
  if (t < 256) {
    unsigned s = 0;
#pragma unroll
    for (int j = 0; j < 32; ++j) s += h[(t << 5) + ((t + j) & 31)];
    if (s) atomicAdd(&ws[WS_HIST1 + t], s);
  }
}

__global__ void __launch_bounds__(256) sel1_kernel(
    const int* __restrict__ maxf, unsigned* __restrict__ ws, long long n) {
  __shared__ unsigned sh4[4];
  __shared__ unsigned sel2[2];
  long long kk = (long long)maxf[0] + 1;
  if (kk > n) {
    if (threadIdx.x == 0) ws[WS_B1] = 0x80u;
    return;
  }
  uint2 r = select_desc256(ws + WS_HIST1, (unsigned)kk, sh4, sel2);
  if (threadIdx.x == 0) { ws[WS_B1] = r.x; ws[WS_K2] = r.y; }
}

__global__ void __launch_bounds__(1024) scatter_kernel(
    const float* __restrict__ e, const float* __restrict__ m, const float* __restrict__ d,
    float* __restrict__ out, unsigned* __restrict__ ws, unsigned cap,
    int e_blks, int m_blks) {
  const int t = threadIdx.x;
  const int bid = blockIdx.x;
  __shared__ float    sh_v[STASH];
  __shared__ unsigned sh_i[STASH];
  __shared__ unsigned sh_cnt;
  __shared__ unsigned sh_base;
  if (t == 0) sh_cnt = 0u;
  const unsigned b1 = ws[WS_B1];
  __syncthreads();
  const float4* in4;
  if (bid < e_blks)               in4 = (const float4*)e + (long long)bid * 2048;
  else if (bid < e_blks + m_blks) in4 = (const float4*)m + (long long)(bid - e_blks) * 2048;
  else                            in4 = (const float4*)d + (long long)(bid - e_blks - m_blks) * 2048;
  const int out_base_v = bid * 2048;
  nfloat4* out4 = (nfloat4*)out + out_base_v;
  float* gcV = (float*)(ws + WS_CAND);
  unsigned* gcI = ws + WS_CAND + cap;
  auto emit1 = [&](float4 f, int v) {
    unsigned kx = fkey(f.x), ky = fkey(f.y), kz = fkey(f.z), kw = fkey(f.w);
    nfloat4 o;
    o.x = ((kx >> 24) >= b1) ? f.x : 0.0f;
    o.y = ((ky >> 24) >= b1) ? f.y : 0.0f;
    o.z = ((kz >> 24) >= b1) ? f.z : 0.0f;
    o.w = ((kw >> 24) >= b1) ? f.w : 0.0f;
    __builtin_nontemporal_store(o, &out4[v]);
    unsigned ks[4] = {kx, ky, kz, kw};
    float fs[4] = {f.x, f.y, f.z, f.w};
#pragma unroll
    for (int cc = 0; cc < 4; ++cc) {
      if ((ks[cc] >> 24) == b1) {
        unsigned idx = (unsigned)(out_base_v + v) * 4u + (unsigned)cc;
        unsigned pos = atomicAdd(&sh_cnt, 1u);
        if (pos < STASH) { sh_v[pos] = fs[cc]; sh_i[pos] = idx; }
        else {
          unsigned g = atomicAdd(&ws[WS_CANDCNT], 1u);
          gcV[g] = fs[cc]; gcI[g] = idx;
        }
      }
    }
  };
  float4 f0 = in4[t];
  float4 f1 = in4[1024 + t];
  emit1(f0, t);
  emit1(f1, 1024 + t);
  __syncthreads();
  if (t == 0) {
    unsigned tot = sh_cnt < STASH ? sh_cnt : STASH;
    sh_base = tot ? atomicAdd(&ws[WS_CANDCNT], tot) : 0u;
    sh_cnt = tot;
  }
  __syncthreads();
  const unsigned tot = sh_cnt;
  const unsigned base = sh_base;
  for (unsigned i = t; i < tot; i += 1024) {
    gcV[base + i] = sh_v[i];
    gcI[base + i] = sh_i[i];
  }
}

__global__ void __launch_bounds__(256) candhist2_kernel(
    unsigned* __restrict__ ws, unsigned cap) {
  const int t = threadIdx.x;
  __shared__ unsigned sh_hist[4096];
  for (int i = t; i < 4096; i += 256) sh_hist[i] = 0u;
  __syncthreads();
  unsigned cnt = ws[WS_CANDCNT]; if (cnt > cap) cnt = cap;
  const float* candV = (const float*)(ws + WS_CAND);
  const unsigned G = gridDim.x * 256;
  for (unsigned i = blockIdx.x * 256 + t; i < cnt; i += G) {
    unsigned u = fkey(candV[i]);
    atomicAdd(&sh_hist[(u >> 12) & 0xFFFu], 1u);
  }
  __syncthreads();
  for (int i = t; i < 4096; i += 256) {
    unsigned v = sh_hist[i];
    if (v) atomicAdd(&ws[WS_HIST2 + i], v);
  }
}

__global__ void __launch_bounds__(256) candhist3_kernel(
    const int* __restrict__ maxf, unsigned* __restrict__ ws, unsigned cap, long long n) {
  const int t = threadIdx.x;
  __shared__ unsigned sh_hist[4096];
  __shared__ unsigned sh4[4];
  __shared__ unsigned sel2[2];
  for (int i = t; i < 4096; i += 256) sh_hist[i] = 0u;
  long long kk = (long long)maxf[0] + 1;
  unsigned pfx;
  if (kk > n) {
    pfx = 0x80u << 12;
    __syncthreads();
  } else {
    unsigned b1 = ws[WS_B1];
    unsigned k2 = ws[WS_K2];
    uint2 r2 = select_desc4096(ws + WS_HIST2, k2, sh4, sel2);
    pfx = (b1 << 12) | r2.x;
    if (blockIdx.x == 0 && t == 0) { ws[WS_PFX] = pfx; ws[WS_K3] = r2.y; }
  }
  __syncthreads();
  unsigned cnt = ws[WS_CANDCNT]; if (cnt > cap) cnt = cap;
  const float* candV = (const float*)(ws + WS_CAND);
  const unsigned G = gridDim.x * 256;
  for (unsigned i = blockIdx.x * 256 + t; i < cnt; i += G) {
    unsigned u = fkey(candV[i]);
    if ((u >> 12) == pfx) atomicAdd(&sh_hist[u & 0xFFFu], 1u);
  }
  __syncthreads();
  for (int i = t; i < 4096; i += 256) {
    unsigned v = sh_hist[i];
    if (v) atomicAdd(&ws[WS_HIST3 + i], v);
  }
}

__global__ void __launch_bounds__(256) fixup_kernel(
    float* __restrict__ out, const int* __restrict__ maxf,
    unsigned* __restrict__ ws, unsigned cap, long long n) {
  const int t = threadIdx.x;
  __shared__ unsigned sh4[4];
  __shared__ unsigned sel2[2];
  long long kk = (long long)maxf[0] + 1;
  float th;
  if (kk > n) {
    th = 0.0f;
    __syncthreads();
  } else {
    unsigned pfx = ws[WS_PFX];
    unsigned k3  = ws[WS_K3];
    uint2 r3 = select_desc4096(ws + WS_HIST3, k3, sh4, sel2);
    th = unkey((pfx << 12) | r3.x);
  }
  unsigned cnt = ws[WS_CANDCNT]; if (cnt > cap) cnt = cap;
  const float* candV = (const float*)(ws + WS_CAND);
  const unsigned* candI = ws + WS_CAND + cap;
  const unsigned G = gridDim.x * 256;
  for (unsigned i = blockIdx.x * 256 + t; i < cnt; i += G) {
    float f = candV[i];
    if (f < th) out[candI[i]] = 0.0f;
  }
}

// =================================== launch ===================================
extern "C" void kernel_launch(void* const* d_in, const int* in_sizes, int n_in,
                              void* d_out, int out_size, void* d_ws, size_t ws_size,
                              hipStream_t stream) {
  const float* e = (const float*)d_in[0];
  const float* m = (const float*)d_in[1];
  const float* d = (const float*)d_in[2];
  const int* maxf = (const int*)d_in[3];
  float* out = (float*)d_out;
  unsigned* ws = (unsigned*)d_ws;

  const long long n0 = in_sizes[0], n1 = in_sizes[1], n2 = in_sizes[2];
  const long long n = n0 + n1 + n2;
  const int n0v = (int)(n0 / 4), n1v = (int)(n1 / 4), n2v = (int)(n2 / 4);

  long long capll = ((long long)(ws_size / 4) - WS_CAND) / 2;
  if (capll < 0) capll = 0;
  if (capll > n) capll = n;
  const unsigned cap = (unsigned)capll;

  const int e_blks = (int)(n0 / 8192), m_blks = (int)(n1 / 8192);
  const int nblocks = (int)(n / 8192);

  // zero ws header (incl. barrier counter) via stream-ordered memset
  hipMemsetAsync(ws, 0, WS_ZEND * sizeof(unsigned), stream);

  // cooperative grid: 2 blocks/CU co-resident
  int maxb = 0;
  if (hipOccupancyMaxActiveBlocksPerMultiprocessor(&maxb, mega_kernel, NTHR, 0) != hipSuccess ||
      maxb < 1) maxb = 1;
  int nb = maxb * 256;
  if (nb > 512) nb = 512;

  void* args[] = {(void*)&e, (void*)&m, (void*)&d, (void*)&maxf, (void*)&out, (void*)&ws,
                  (void*)&cap, (void*)&n0v, (void*)&n1v, (void*)&n2v,
                  (void*)&e_blks, (void*)&m_blks, (void*)&nblocks, (void*)&n};
  hipError_t err = hipLaunchCooperativeKernel(mega_kernel, dim3(nb), dim3(NTHR),
                                              args, 0, stream);
  if (err != hipSuccess) {
    // fallback: proven R2 chain (minus zero_ws; memset above covers it)
    hist1_kernel<<<512, 1024, 0, stream>>>(e, m, d, n0v, n1v, n2v, ws);
    sel1_kernel<<<1, 256, 0, stream>>>(maxf, ws, n);
    scatter_kernel<<<nblocks, 1024, 0, stream>>>(e, m, d, out, ws, cap, e_blks, m_blks);
    candhist2_kernel<<<128, 256, 0, stream>>>(ws, cap);
    candhist3_kernel<<<128, 256, 0, stream>>>(maxf, ws, cap, n);
    fixup_kernel<<<256, 256, 0, stream>>>(out, maxf, ws, cap, n);
  }
}

// Round 5
// 225.529 us; speedup vs baseline: 3.4561x; 3.4561x over previous
//
#include <hip/hip_runtime.h>

typedef float nfloat4 __attribute__((ext_vector_type(4)));

// ---------------- workspace layout (u32 indices) ----------------
#define WS_CANDCNT 0
#define WS_B1      1
#define WS_K2      2          // written by hist1's last block
#define WS_PFX     3          // written by candhist2's last block
#define WS_K3      4
#define WS_TH      5          // exact threshold bits, written by candhist3's last block
#define WS_DONE1   8          // done-counters for last-block detection
#define WS_DONE2   9
#define WS_DONE3   10
#define WS_HIST1   16
#define WS_HIST2   272            // 16 + 256
#define WS_HIST3   4368           // 272 + 4096
#define WS_ZEND    8464           // end of memset-zeroed header
#define WS_CAND    8464           // candV[cap] floats, then candI[cap] u32

#define STASH 2048

// Monotone key: larger float -> larger unsigned.
__device__ __forceinline__ unsigned fkey(float f) {
  unsigned x = __float_as_uint(f);
  return x ^ ((x & 0x80000000u) ? 0xFFFFFFFFu : 0x80000000u);
}
__device__ __forceinline__ float unkey(unsigned u) {
  unsigned x = u ^ ((u & 0x80000000u) ? 0x80000000u : 0xFFFFFFFFu);
  return __uint_as_float(x);
}

// ---------------- 256-thread select primitives (proven R0-R2) ----------------
__device__ __forceinline__ unsigned block_scan_incl(unsigned v, unsigned* sh4) {
  const int t = threadIdx.x;
  unsigned p = v;
#pragma unroll
  for (int off = 1; off < 64; off <<= 1) {
    unsigned y = __shfl_up(p, off);
    if ((t & 63) >= off) p += y;
  }
  if ((t & 63) == 63) sh4[t >> 6] = p;
  __syncthreads();
  unsigned wo = 0;
  for (int w = 0; w < (t >> 6); ++w) wo += sh4[w];
  __syncthreads();
  return p + wo;
}

__device__ __forceinline__ uint2 select_desc4096(const unsigned* __restrict__ gh,
                                                 unsigned k, unsigned* sh4, unsigned* sel2) {
  const int t = threadIdx.x;
  unsigned loc[16]; unsigned s = 0;
  const int base = 4095 - t * 16;
#pragma unroll
  for (int j = 0; j < 16; ++j) { unsigned c = gh[base - j]; loc[j] = c; s += c; }
  unsigned incl = block_scan_incl(s, sh4);
  unsigned excl = incl - s;
  if (excl < k && incl >= k) {
    unsigned cum = excl; int j = 0;
    while (cum + loc[j] < k) { cum += loc[j]; ++j; }
    sel2[0] = (unsigned)(base - j); sel2[1] = k - cum;
  }
  __syncthreads();
  uint2 r; r.x = sel2[0]; r.y = sel2[1];
  __syncthreads();
  return r;
}

// ---------------- 1024-thread select over 256 buckets (for hist1 epilogue) ----
__device__ __forceinline__ unsigned scan1024(unsigned v, unsigned* sh16) {
  const int t = threadIdx.x;
  unsigned p = v;
#pragma unroll
  for (int off = 1; off < 64; off <<= 1) {
    unsigned y = __shfl_up(p, off);
    if ((t & 63) >= off) p += y;
  }
  if ((t & 63) == 63) sh16[t >> 6] = p;
  __syncthreads();
  unsigned wo = 0;
  for (int w = 0; w < (t >> 6); ++w) wo += sh16[w];
  __syncthreads();
  return p + wo;
}

__device__ __forceinline__ uint2 sel256_w(const unsigned* __restrict__ gh, unsigned k,
                                          unsigned* sh16, unsigned* sel2) {
  const int t = threadIdx.x;
  unsigned cnt = (t < 256) ? gh[255 - t] : 0u;
  unsigned incl = scan1024(cnt, sh16);
  unsigned excl = incl - cnt;
  if (t < 256 && excl < k && incl >= k) { sel2[0] = (unsigned)(255 - t); sel2[1] = k - excl; }
  __syncthreads();
  uint2 r; r.x = sel2[0]; r.y = sel2[1];
  __syncthreads();
  return r;
}

// K1: 8-bit MSB histogram (proven body) + LAST-BLOCK select1 epilogue.
// Last-block pattern: fence -> done-counter atomicAdd -> only the block that
// sees old==NB-1 proceeds (no spinning; R3/R4 proved grid-wide spin costs
// 200-300us/barrier on this stack regardless of implementation).
__global__ void __launch_bounds__(1024) hist1_kernel(
    const float* __restrict__ e, const float* __restrict__ m,
    const float* __restrict__ d, int n0v, int n1v, int n2v,
    unsigned* __restrict__ ws, const int* __restrict__ maxf, long long n) {
  __shared__ unsigned h[256 * 32];
  __shared__ unsigned sh16[16];
  __shared__ unsigned sel2[2];
  __shared__ unsigned sh_last;
  for (int i = threadIdx.x; i < 256 * 32; i += 1024) h[i] = 0u;
  __syncthreads();
  const unsigned sub = threadIdx.x & 31u;
  const int gid = blockIdx.x * 1024 + threadIdx.x;
  const int G = gridDim.x * 1024;

  auto acc1 = [&](float4 f) {
    atomicAdd(&h[((fkey(f.x) >> 24) << 5) | sub], 1u);
    atomicAdd(&h[((fkey(f.y) >> 24) << 5) | sub], 1u);
    atomicAdd(&h[((fkey(f.z) >> 24) << 5) | sub], 1u);
    atomicAdd(&h[((fkey(f.w) >> 24) << 5) | sub], 1u);
  };
  auto sweep = [&](const float* src, int nv) {
    const float4* a4 = (const float4*)src;
    int v = gid;
    for (; v + 3 * G < nv; v += 4 * G) {
      float4 f0 = a4[v]; float4 f1 = a4[v + G];
      float4 f2 = a4[v + 2 * G]; float4 f3 = a4[v + 3 * G];
      acc1(f0); acc1(f1); acc1(f2); acc1(f3);
    }
    for (; v < nv; v += G) acc1(a4[v]);
  };
  sweep(e, n0v); sweep(m, n1v); sweep(d, n2v);
  __syncthreads();
  const int t = threadIdx.x;
  if (t < 256) {
    unsigned s = 0;
#pragma unroll
    for (int j = 0; j < 32; ++j) s += h[(t << 5) + ((t + j) & 31)];
    if (s) atomicAdd(&ws[WS_HIST1 + t], s);
  }
  __syncthreads();
  // ---- last-block select1 ----
  if (t == 0) {
    __threadfence();
    unsigned old = atomicAdd(&ws[WS_DONE1], 1u);
    sh_last = (old == gridDim.x - 1u) ? 1u : 0u;
  }
  __syncthreads();
  if (sh_last) {
    __threadfence();  // ensure we read all blocks' flushed hist
    long long kk = (long long)maxf[0] + 1;
    if (kk > n) {
      if (t == 0) ws[WS_B1] = 0x80u;  // thresh = +0.0f path (k2 unused)
    } else {
      uint2 r = sel256_w(ws + WS_HIST1, (unsigned)kk, sh16, sel2);
      if (t == 0) { ws[WS_B1] = r.x; ws[WS_K2] = r.y; }
    }
  }
}

// K2: near-pure stream (proven R0/R2 body, untouched). 1024 thr x 2 float4,
// tile 8192; b1 via one scalar load; candidate push to LDS stash; one global
// atomic per block. NO per-candidate global hist atomics (R1 lesson).
__global__ void __launch_bounds__(1024) scatter_kernel(
    const float* __restrict__ e, const float* __restrict__ m, const float* __restrict__ d,
    float* __restrict__ out, unsigned* __restrict__ ws, unsigned cap,
    int e_blks, int m_blks) {
  const int t = threadIdx.x;
  const int bid = blockIdx.x;
  __shared__ float    sh_v[STASH];
  __shared__ unsigned sh_i[STASH];
  __shared__ unsigned sh_cnt;
  __shared__ unsigned sh_base;
  if (t == 0) sh_cnt = 0u;
  const unsigned b1 = ws[WS_B1];
  __syncthreads();
  const float4* in4;
  if (bid < e_blks)               in4 = (const float4*)e + (long long)bid * 2048;
  else if (bid < e_blks + m_blks) in4 = (const float4*)m + (long long)(bid - e_blks) * 2048;
  else                            in4 = (const float4*)d + (long long)(bid - e_blks - m_blks) * 2048;
  const int out_base_v = bid * 2048;
  nfloat4* out4 = (nfloat4*)out + out_base_v;
  float* gcV = (float*)(ws + WS_CAND);
  unsigned* gcI = ws + WS_CAND + cap;
  auto emit1 = [&](float4 f, int v) {
    unsigned kx = fkey(f.x), ky = fkey(f.y), kz = fkey(f.z), kw = fkey(f.w);
    nfloat4 o;
    o.x = ((kx >> 24) >= b1) ? f.x : 0.0f;
    o.y = ((ky >> 24) >= b1) ? f.y : 0.0f;
    o.z = ((kz >> 24) >= b1) ? f.z : 0.0f;
    o.w = ((kw >> 24) >= b1) ? f.w : 0.0f;
    __builtin_nontemporal_store(o, &out4[v]);
    unsigned ks[4] = {kx, ky, kz, kw};
    float fs[4] = {f.x, f.y, f.z, f.w};
#pragma unroll
    for (int cc = 0; cc < 4; ++cc) {
      if ((ks[cc] >> 24) == b1) {
        unsigned idx = (unsigned)(out_base_v + v) * 4u + (unsigned)cc;
        unsigned pos = atomicAdd(&sh_cnt, 1u);
        if (pos < STASH) { sh_v[pos] = fs[cc]; sh_i[pos] = idx; }
        else {  // statistically never; correct fallback
          unsigned g = atomicAdd(&ws[WS_CANDCNT], 1u);
          gcV[g] = fs[cc]; gcI[g] = idx;
        }
      }
    }
  };
  float4 f0 = in4[t];
  float4 f1 = in4[1024 + t];
  emit1(f0, t);
  emit1(f1, 1024 + t);
  __syncthreads();
  if (t == 0) {
    unsigned tot = sh_cnt < STASH ? sh_cnt : STASH;
    sh_base = tot ? atomicAdd(&ws[WS_CANDCNT], tot) : 0u;
    sh_cnt = tot;
  }
  __syncthreads();
  const unsigned tot = sh_cnt;
  const unsigned base = sh_base;
  for (unsigned i = t; i < tot; i += 1024) {
    gcV[base + i] = sh_v[i];
    gcI[base + i] = sh_i[i];
  }
}

// K3a: stage-2 12-bit histogram over candidates (128 blocks: keeps per-block
// LDS aggregation high, R1 lesson) + LAST-BLOCK select2 -> (pfx,k3).
__global__ void __launch_bounds__(256) candhist2_kernel(
    const int* __restrict__ maxf, unsigned* __restrict__ ws, unsigned cap, long long n) {
  const int t = threadIdx.x;
  __shared__ unsigned sh_hist[4096];
  __shared__ unsigned sh4[4];
  __shared__ unsigned sel2[2];
  __shared__ unsigned sh_last;
  for (int i = t; i < 4096; i += 256) sh_hist[i] = 0u;
  __syncthreads();
  unsigned cnt = ws[WS_CANDCNT]; if (cnt > cap) cnt = cap;
  const float* candV = (const float*)(ws + WS_CAND);
  const unsigned G = gridDim.x * 256;
  for (unsigned i = blockIdx.x * 256 + t; i < cnt; i += G) {
    unsigned u = fkey(candV[i]);
    atomicAdd(&sh_hist[(u >> 12) & 0xFFFu], 1u);
  }
  __syncthreads();
  for (int i = t; i < 4096; i += 256) {
    unsigned v = sh_hist[i];
    if (v) atomicAdd(&ws[WS_HIST2 + i], v);
  }
  __syncthreads();
  // ---- last-block select2 ----
  if (t == 0) {
    __threadfence();
    unsigned old = atomicAdd(&ws[WS_DONE2], 1u);
    sh_last = (old == gridDim.x - 1u) ? 1u : 0u;
  }
  __syncthreads();
  if (sh_last) {
    __threadfence();
    long long kk = (long long)maxf[0] + 1;
    if (kk <= n) {
      unsigned b1 = ws[WS_B1];
      unsigned k2 = ws[WS_K2];
      uint2 r2 = select_desc4096(ws + WS_HIST2, k2, sh4, sel2);
      if (t == 0) { ws[WS_PFX] = (b1 << 12) | r2.x; ws[WS_K3] = r2.y; }
    }
    // kk > n: WS_PFX stays 0 (memset); candhist3 matches nothing; th=0 path.
  }
}

// K3b: stage-3 12-bit histogram of pfx-matching candidates (pfx read directly,
// no select prologue) + LAST-BLOCK select3 -> exact threshold bits in WS_TH.
__global__ void __launch_bounds__(256) candhist3_kernel(
    const int* __restrict__ maxf, unsigned* __restrict__ ws, unsigned cap, long long n) {
  const int t = threadIdx.x;
  __shared__ unsigned sh_hist[4096];
  __shared__ unsigned sh4[4];
  __shared__ unsigned sel2[2];
  __shared__ unsigned sh_last;
  for (int i = t; i < 4096; i += 256) sh_hist[i] = 0u;
  __syncthreads();
  const unsigned pfx = ws[WS_PFX];   // uniform scalar load (dispatch-boundary handoff)
  unsigned cnt = ws[WS_CANDCNT]; if (cnt > cap) cnt = cap;
  const float* candV = (const float*)(ws + WS_CAND);
  const unsigned G = gridDim.x * 256;
  for (unsigned i = blockIdx.x * 256 + t; i < cnt; i += G) {
    unsigned u = fkey(candV[i]);
    if ((u >> 12) == pfx) atomicAdd(&sh_hist[u & 0xFFFu], 1u);
  }
  __syncthreads();
  for (int i = t; i < 4096; i += 256) {
    unsigned v = sh_hist[i];
    if (v) atomicAdd(&ws[WS_HIST3 + i], v);
  }
  __syncthreads();
  // ---- last-block select3 -> exact threshold ----
  if (t == 0) {
    __threadfence();
    unsigned old = atomicAdd(&ws[WS_DONE3], 1u);
    sh_last = (old == gridDim.x - 1u) ? 1u : 0u;
  }
  __syncthreads();
  if (sh_last) {
    __threadfence();
    long long kk = (long long)maxf[0] + 1;
    if (kk > n) {
      if (t == 0) ws[WS_TH] = __float_as_uint(0.0f);
    } else {
      unsigned k3 = ws[WS_K3];
      uint2 r3 = select_desc4096(ws + WS_HIST3, k3, sh4, sel2);
      if (t == 0) ws[WS_TH] = __float_as_uint(unkey((pfx << 12) | r3.x));
    }
  }
}

// K4: pure stream over candidates; threshold read directly (no select).
__global__ void __launch_bounds__(256) fixup_kernel(
    float* __restrict__ out, unsigned* __restrict__ ws, unsigned cap) {
  const int t = threadIdx.x;
  const float th = __uint_as_float(ws[WS_TH]);
  unsigned cnt = ws[WS_CANDCNT]; if (cnt > cap) cnt = cap;
  const float* candV = (const float*)(ws + WS_CAND);
  const unsigned* candI = ws + WS_CAND + cap;
  const unsigned G = gridDim.x * 256;
  for (unsigned i = blockIdx.x * 256 + t; i < cnt; i += G) {
    float f = candV[i];
    if (f < th) out[candI[i]] = 0.0f;
  }
}

// =================================== launch ===================================
extern "C" void kernel_launch(void* const* d_in, const int* in_sizes, int n_in,
                              void* d_out, int out_size, void* d_ws, size_t ws_size,
                              hipStream_t stream) {
  const float* e = (const float*)d_in[0];
  const float* m = (const float*)d_in[1];
  const float* d = (const float*)d_in[2];
  const int* maxf = (const int*)d_in[3];
  float* out = (float*)d_out;
  unsigned* ws = (unsigned*)d_ws;

  const long long n0 = in_sizes[0], n1 = in_sizes[1], n2 = in_sizes[2];
  const long long n = n0 + n1 + n2;
  const int n0v = (int)(n0 / 4), n1v = (int)(n1 / 4), n2v = (int)(n2 / 4);

  long long capll = ((long long)(ws_size / 4) - WS_CAND) / 2;
  if (capll < 0) capll = 0;
  if (capll > n) capll = n;   // cap >= n in this harness => no overflow possible
  const unsigned cap = (unsigned)capll;

  const int e_blks = (int)(n0 / 8192), m_blks = (int)(n1 / 8192);
  const int nblocks = (int)(n / 8192);   // sizes divide exactly: 2048+512+128

  hipMemsetAsync(ws, 0, WS_ZEND * sizeof(unsigned), stream);
  hist1_kernel<<<512, 1024, 0, stream>>>(e, m, d, n0v, n1v, n2v, ws, maxf, n);
  scatter_kernel<<<nblocks, 1024, 0, stream>>>(e, m, d, out, ws, cap, e_blks, m_blks);
  candhist2_kernel<<<128, 256, 0, stream>>>(maxf, ws, cap, n);
  candhist3_kernel<<<128, 256, 0, stream>>>(maxf, ws, cap, n);
  fixup_kernel<<<256, 256, 0, stream>>>(out, ws, cap);
}

// Round 6
// 212.216 us; speedup vs baseline: 3.6729x; 1.0627x over previous
//
#include <hip/hip_runtime.h>

typedef float nfloat4 __attribute__((ext_vector_type(4)));

// ---------------- workspace layout (u32 indices) ----------------
// R6: replicated global histograms. R5 measured hist1 at 51.6us / 1.7TB/s with
// an idle machine; the cost is the flush: 512 blocks' nonzero buckets concentrate
// on 1-2 L2 lines (normal data => ~30 hot buckets), ~4K same-line global atomics
// ~= 30us (calibrated from R1's 500K-atomic/120us regression). Replicas spread
// the collisions 32x / 8x.
#define WS_CANDCNT 0
#define WS_B1      1
#define WS_K2      2
#define WS_PFX     3
#define WS_K3      4
#define H1_REP     32
#define H2_REP     8
#define WS_HIST1R  16                        // [32][256]
#define WS_HIST2R  (16 + H1_REP * 256)       // [8][4096]  (= 8208)
#define WS_HIST3   (WS_HIST2R + H2_REP * 4096)   // 40976 (single copy: ~empty flush)
#define WS_ZEND    (WS_HIST3 + 4096)             // 45072
#define WS_CAND    WS_ZEND                   // candV[cap] floats, then candI[cap] u32

#define STASH 2048

// Monotone key: larger float -> larger unsigned.
__device__ __forceinline__ unsigned fkey(float f) {
  unsigned x = __float_as_uint(f);
  return x ^ ((x & 0x80000000u) ? 0xFFFFFFFFu : 0x80000000u);
}
__device__ __forceinline__ float unkey(unsigned u) {
  unsigned x = u ^ ((u & 0x80000000u) ? 0x80000000u : 0xFFFFFFFFu);
  return __uint_as_float(x);
}

// inclusive scan over 256 threads (4 waves); sh4 has >=4 slots. blockDim==256 only.
__device__ __forceinline__ unsigned block_scan_incl(unsigned v, unsigned* sh4) {
  const int t = threadIdx.x;
  unsigned p = v;
#pragma unroll
  for (int off = 1; off < 64; off <<= 1) {
    unsigned y = __shfl_up(p, off);
    if ((t & 63) >= off) p += y;
  }
  if ((t & 63) == 63) sh4[t >> 6] = p;
  __syncthreads();
  unsigned wo = 0;
  for (int w = 0; w < (t >> 6); ++w) wo += sh4[w];
  __syncthreads();
  return p + wo;
}

// k-th largest over 256-bucket hist (descending); blockDim==256.
__device__ __forceinline__ uint2 select_desc256(const unsigned* __restrict__ gh,
                                                unsigned k, unsigned* sh4, unsigned* sel2) {
  const int t = threadIdx.x;
  unsigned cnt = gh[255 - t];
  unsigned incl = block_scan_incl(cnt, sh4);
  unsigned excl = incl - cnt;
  if (excl < k && incl >= k) { sel2[0] = (unsigned)(255 - t); sel2[1] = k - excl; }
  __syncthreads();
  uint2 r; r.x = sel2[0]; r.y = sel2[1];
  __syncthreads();
  return r;
}

// k-th largest over 4096-bucket hist (descending); verified logic.
__device__ __forceinline__ uint2 select_desc4096(const unsigned* __restrict__ gh,
                                                 unsigned k, unsigned* sh4, unsigned* sel2) {
  const int t = threadIdx.x;
  unsigned loc[16]; unsigned s = 0;
  const int base = 4095 - t * 16;
#pragma unroll
  for (int j = 0; j < 16; ++j) { unsigned c = gh[base - j]; loc[j] = c; s += c; }
  unsigned incl = block_scan_incl(s, sh4);
  unsigned excl = incl - s;
  if (excl < k && incl >= k) {
    unsigned cum = excl; int j = 0;
    while (cum + loc[j] < k) { cum += loc[j]; ++j; }
    sel2[0] = (unsigned)(base - j); sel2[1] = k - cum;
  }
  __syncthreads();
  uint2 r; r.x = sel2[0]; r.y = sel2[1];
  __syncthreads();
  return r;
}

__global__ void zero_ws(unsigned* __restrict__ ws) {
  int i = blockIdx.x * blockDim.x + threadIdx.x;
  if (i < WS_ZEND) ws[i] = 0u;
}

// K1: 8-bit MSB histogram (proven body). FLUSH now goes to replica (bid&31):
// same-address global-atomic collisions drop 512 -> 16 per bucket.
__global__ void __launch_bounds__(1024) hist1_kernel(
    const float* __restrict__ e, const float* __restrict__ m,
    const float* __restrict__ d, int n0v, int n1v, int n2v,
    unsigned* __restrict__ ws) {
  __shared__ unsigned h[256 * 32];
  for (int i = threadIdx.x; i < 256 * 32; i += 1024) h[i] = 0u;
  __syncthreads();
  const unsigned sub = threadIdx.x & 31u;
  const int gid = blockIdx.x * 1024 + threadIdx.x;
  const int G = gridDim.x * 1024;

  auto acc1 = [&](float4 f) {
    atomicAdd(&h[((fkey(f.x) >> 24) << 5) | sub], 1u);
    atomicAdd(&h[((fkey(f.y) >> 24) << 5) | sub], 1u);
    atomicAdd(&h[((fkey(f.z) >> 24) << 5) | sub], 1u);
    atomicAdd(&h[((fkey(f.w) >> 24) << 5) | sub], 1u);
  };
  auto sweep = [&](const float* src, int nv) {
    const float4* a4 = (const float4*)src;
    int v = gid;
    for (; v + 3 * G < nv; v += 4 * G) {
      float4 f0 = a4[v]; float4 f1 = a4[v + G];
      float4 f2 = a4[v + 2 * G]; float4 f3 = a4[v + 3 * G];
      acc1(f0); acc1(f1); acc1(f2); acc1(f3);
    }
    for (; v < nv; v += G) acc1(a4[v]);
  };
  sweep(e, n0v); sweep(m, n1v); sweep(d, n2v);
  __syncthreads();
  const int t = threadIdx.x;
  if (t < 256) {
    unsigned s = 0;
#pragma unroll
    for (int j = 0; j < 32; ++j) s += h[(t << 5) + ((t + j) & 31)];
    if (s) atomicAdd(&ws[WS_HIST1R + (blockIdx.x & (H1_REP - 1)) * 256 + t], s);
  }
}

// K1b: reduce 32 replicas -> LDS, then select1 -> (b1, k2).
__global__ void __launch_bounds__(256) sel1_kernel(
    const int* __restrict__ maxf, unsigned* __restrict__ ws, long long n) {
  __shared__ unsigned h256[256];
  __shared__ unsigned sh4[4];
  __shared__ unsigned sel2[2];
  const int t = threadIdx.x;
  unsigned s = 0;
#pragma unroll
  for (int r = 0; r < H1_REP; ++r) s += ws[WS_HIST1R + r * 256 + t];
  h256[t] = s;
  __syncthreads();
  long long kk = (long long)maxf[0] + 1;
  if (kk > n) {
    if (t == 0) ws[WS_B1] = 0x80u;  // thresh = +0.0f path
    return;
  }
  uint2 r = select_desc256(h256, (unsigned)kk, sh4, sel2);
  if (t == 0) { ws[WS_B1] = r.x; ws[WS_K2] = r.y; }
}

// K2: near-pure stream (proven R0/R2 body, untouched).
__global__ void __launch_bounds__(1024) scatter_kernel(
    const float* __restrict__ e, const float* __restrict__ m, const float* __restrict__ d,
    float* __restrict__ out, unsigned* __restrict__ ws, unsigned cap,
    int e_blks, int m_blks) {
  const int t = threadIdx.x;
  const int bid = blockIdx.x;
  __shared__ float    sh_v[STASH];
  __shared__ unsigned sh_i[STASH];
  __shared__ unsigned sh_cnt;
  __shared__ unsigned sh_base;
  if (t == 0) sh_cnt = 0u;
  const unsigned b1 = ws[WS_B1];
  __syncthreads();
  const float4* in4;
  if (bid < e_blks)               in4 = (const float4*)e + (long long)bid * 2048;
  else if (bid < e_blks + m_blks) in4 = (const float4*)m + (long long)(bid - e_blks) * 2048;
  else                            in4 = (const float4*)d + (long long)(bid - e_blks - m_blks) * 2048;
  const int out_base_v = bid * 2048;
  nfloat4* out4 = (nfloat4*)out + out_base_v;
  float* gcV = (float*)(ws + WS_CAND);
  unsigned* gcI = ws + WS_CAND + cap;
  auto emit1 = [&](float4 f, int v) {
    unsigned kx = fkey(f.x), ky = fkey(f.y), kz = fkey(f.z), kw = fkey(f.w);
    nfloat4 o;
    o.x = ((kx >> 24) >= b1) ? f.x : 0.0f;
    o.y = ((ky >> 24) >= b1) ? f.y : 0.0f;
    o.z = ((kz >> 24) >= b1) ? f.z : 0.0f;
    o.w = ((kw >> 24) >= b1) ? f.w : 0.0f;
    __builtin_nontemporal_store(o, &out4[v]);
    unsigned ks[4] = {kx, ky, kz, kw};
    float fs[4] = {f.x, f.y, f.z, f.w};
#pragma unroll
    for (int cc = 0; cc < 4; ++cc) {
      if ((ks[cc] >> 24) == b1) {
        unsigned idx = (unsigned)(out_base_v + v) * 4u + (unsigned)cc;
        unsigned pos = atomicAdd(&sh_cnt, 1u);
        if (pos < STASH) { sh_v[pos] = fs[cc]; sh_i[pos] = idx; }
        else {  // statistically never; correct fallback
          unsigned g = atomicAdd(&ws[WS_CANDCNT], 1u);
          gcV[g] = fs[cc]; gcI[g] = idx;
        }
      }
    }
  };
  float4 f0 = in4[t];
  float4 f1 = in4[1024 + t];
  emit1(f0, t);
  emit1(f1, 1024 + t);
  __syncthreads();
  if (t == 0) {
    unsigned tot = sh_cnt < STASH ? sh_cnt : STASH;
    sh_base = tot ? atomicAdd(&ws[WS_CANDCNT], tot) : 0u;
    sh_cnt = tot;
  }
  __syncthreads();
  const unsigned tot = sh_cnt;
  const unsigned base = sh_base;
  for (unsigned i = t; i < tot; i += 1024) {
    gcV[base + i] = sh_v[i];
    gcI[base + i] = sh_i[i];
  }
}

// K3a: stage-2 12-bit histogram over candidates (128 blocks, LDS-aggregated;
// R1 lesson). FLUSH to replica (bid&7): same-line collisions drop 8x.
__global__ void __launch_bounds__(256) candhist2_kernel(
    unsigned* __restrict__ ws, unsigned cap) {
  const int t = threadIdx.x;
  __shared__ unsigned sh_hist[4096];
  for (int i = t; i < 4096; i += 256) sh_hist[i] = 0u;
  __syncthreads();
  unsigned cnt = ws[WS_CANDCNT]; if (cnt > cap) cnt = cap;
  const float* candV = (const float*)(ws + WS_CAND);
  const unsigned G = gridDim.x * 256;
  for (unsigned i = blockIdx.x * 256 + t; i < cnt; i += G) {
    unsigned u = fkey(candV[i]);
    atomicAdd(&sh_hist[(u >> 12) & 0xFFFu], 1u);
  }
  __syncthreads();
  const unsigned rep = (blockIdx.x & (H2_REP - 1)) * 4096u;
  for (int i = t; i < 4096; i += 256) {
    unsigned v = sh_hist[i];
    if (v) atomicAdd(&ws[WS_HIST2R + rep + i], v);
  }
}

// K3b: prologue sums the 8 HIST2 replicas into LDS, does ONE select -> (pfx,k3),
// publishes them; body histograms low 12 bits of pfx-matching candidates.
__global__ void __launch_bounds__(256) candhist3_kernel(
    const int* __restrict__ maxf, unsigned* __restrict__ ws, unsigned cap, long long n) {
  const int t = threadIdx.x;
  __shared__ unsigned sh_hist[4096];
  __shared__ unsigned sh4[4];
  __shared__ unsigned sel2[2];

  long long kk = (long long)maxf[0] + 1;
  unsigned pfx;
  if (kk > n) {
    pfx = 0x80u << 12;
  } else {
    for (int i = t; i < 4096; i += 256) {
      unsigned s = 0;
#pragma unroll
      for (int r = 0; r < H2_REP; ++r) s += ws[WS_HIST2R + r * 4096 + i];
      sh_hist[i] = s;
    }
    __syncthreads();
    unsigned b1 = ws[WS_B1];
    unsigned k2 = ws[WS_K2];
    uint2 r2 = select_desc4096(sh_hist, k2, sh4, sel2);
    pfx = (b1 << 12) | r2.x;
    if (blockIdx.x == 0 && t == 0) { ws[WS_PFX] = pfx; ws[WS_K3] = r2.y; }
    __syncthreads();
  }
  // (re)zero LDS hist for stage-3 accumulation
  for (int i = t; i < 4096; i += 256) sh_hist[i] = 0u;
  __syncthreads();

  unsigned cnt = ws[WS_CANDCNT]; if (cnt > cap) cnt = cap;
  const float* candV = (const float*)(ws + WS_CAND);
  const unsigned G = gridDim.x * 256;
  for (unsigned i = blockIdx.x * 256 + t; i < cnt; i += G) {
    unsigned u = fkey(candV[i]);
    if ((u >> 12) == pfx) atomicAdd(&sh_hist[u & 0xFFFu], 1u);
  }
  __syncthreads();
  // stage-3 hist is ~99% empty (only ~cnt/4096 candidates match pfx): the if(v)
  // skip keeps this flush tiny -> single global copy is safe.
  for (int i = t; i < 4096; i += 256) {
    unsigned v = sh_hist[i];
    if (v) atomicAdd(&ws[WS_HIST3 + i], v);
  }
}

// K4: prologue reads (pfx,k3), ONE select over HIST3 -> exact threshold; body
// zeroes provisionally-kept candidates below it.
__global__ void __launch_bounds__(256) fixup_kernel(
    float* __restrict__ out, const int* __restrict__ maxf,
    unsigned* __restrict__ ws, unsigned cap, long long n) {
  const int t = threadIdx.x;
  __shared__ unsigned sh4[4];
  __shared__ unsigned sel2[2];

  long long kk = (long long)maxf[0] + 1;
  float th;
  if (kk > n) {
    th = 0.0f;
    __syncthreads();
  } else {
    unsigned pfx = ws[WS_PFX];
    unsigned k3  = ws[WS_K3];
    uint2 r3 = select_desc4096(ws + WS_HIST3, k3, sh4, sel2);
    th = unkey((pfx << 12) | r3.x);
  }

  unsigned cnt = ws[WS_CANDCNT]; if (cnt > cap) cnt = cap;
  const float* candV = (const float*)(ws + WS_CAND);
  const unsigned* candI = ws + WS_CAND + cap;
  const unsigned G = gridDim.x * 256;
  for (unsigned i = blockIdx.x * 256 + t; i < cnt; i += G) {
    float f = candV[i];
    if (f < th) out[candI[i]] = 0.0f;
  }
}

extern "C" void kernel_launch(void* const* d_in, const int* in_sizes, int n_in,
                              void* d_out, int out_size, void* d_ws, size_t ws_size,
                              hipStream_t stream) {
  const float* e = (const float*)d_in[0];
  const float* m = (const float*)d_in[1];
  const float* d = (const float*)d_in[2];
  const int* maxf = (const int*)d_in[3];
  float* out = (float*)d_out;
  unsigned* ws = (unsigned*)d_ws;

  const long long n0 = in_sizes[0], n1 = in_sizes[1], n2 = in_sizes[2];
  const long long n = n0 + n1 + n2;
  const int n0v = (int)(n0 / 4), n1v = (int)(n1 / 4), n2v = (int)(n2 / 4);

  long long capll = ((long long)(ws_size / 4) - WS_CAND) / 2;
  if (capll < 0) capll = 0;
  if (capll > n) capll = n;   // candidates (~500K) << cap in this harness
  const unsigned cap = (unsigned)capll;

  const int e_blks = (int)(n0 / 8192), m_blks = (int)(n1 / 8192);
  const int nblocks = (int)(n / 8192);   // sizes divide exactly: 2048+512+128

  zero_ws<<<(WS_ZEND + 255) / 256, 256, 0, stream>>>(ws);
  hist1_kernel<<<512, 1024, 0, stream>>>(e, m, d, n0v, n1v, n2v, ws);
  sel1_kernel<<<1, 256, 0, stream>>>(maxf, ws, n);
  scatter_kernel<<<nblocks, 1024, 0, stream>>>(e, m, d, out, ws, cap, e_blks, m_blks);
  candhist2_kernel<<<128, 256, 0, stream>>>(ws, cap);
  candhist3_kernel<<<128, 256, 0, stream>>>(maxf, ws, cap, n);
  fixup_kernel<<<256, 256, 0, stream>>>(out, maxf, ws, cap, n);
}